// Round 5
// baseline (10834.196 us; speedup 1.0000x reference)
//
#include <hip/hip_runtime.h>

#define EPSF 1e-5f

// workspace layout (bytes)
#define ODD_OFF   0LL                  // X_norm, Y1, Y3, Y5 (max 104,857,600)
#define EVEN_OFF  104857600LL          // Y0, Y2, Y4, Y6     (max 41,943,040)
#define WT_OFF    146800640LL          // transposed weights (16,304,848)
#define STATS_OFF 163105488LL          // stats/scales (1024 floats)
#define WS_NEED   163110000LL

// ---------------------------------------------------------------- utility
__global__ void k_zero_out(float* __restrict__ out, int n) {
    for (int i = blockIdx.x * blockDim.x + threadIdx.x; i < n; i += gridDim.x * blockDim.x)
        out[i] = 0.f;
}

__device__ __forceinline__ float waveReduceSum(float v) {
    v += __shfl_down(v, 32);
    v += __shfl_down(v, 16);
    v += __shfl_down(v, 8);
    v += __shfl_down(v, 4);
    v += __shfl_down(v, 2);
    v += __shfl_down(v, 1);
    return v;
}

__global__ void k_input_stats(const float* __restrict__ x, int n, float* __restrict__ stats) {
    float s = 0.f, s2 = 0.f;
    for (int i = blockIdx.x * blockDim.x + threadIdx.x; i < n; i += gridDim.x * blockDim.x) {
        float v = x[i];
        s += v;
        s2 += v * v;
    }
    __shared__ float sh0[4], sh1[4];
    s = waveReduceSum(s);
    s2 = waveReduceSum(s2);
    int lane = threadIdx.x & 63, w = threadIdx.x >> 6;
    if (lane == 0) { sh0[w] = s; sh1[w] = s2; }
    __syncthreads();
    if (threadIdx.x == 0) {
        float a = 0.f, b = 0.f;
        int nw = blockDim.x >> 6;
        for (int i = 0; i < nw; i++) { a += sh0[i]; b += sh1[i]; }
        atomicAdd(&stats[0], a);
        atomicAdd(&stats[1], b);
    }
}

__global__ void k_normalize(const float* __restrict__ x, int n, float invn,
                            const float* __restrict__ stats, float* __restrict__ y) {
    float mu = stats[0] * invn;
    float var = stats[1] * invn - mu * mu;
    float sc = rsqrtf(var + EPSF);
    for (int i = blockIdx.x * blockDim.x + threadIdx.x; i < n; i += gridDim.x * blockDim.x)
        y[i] = (x[i] - mu) * sc;
}

// w[co][ci][tap] -> wt[(ci*343+tap)*cop + co]  (pad co to cop with zeros)
__global__ void k_wtrans(const float* __restrict__ w, int cout, int cin, int cop,
                         float* __restrict__ wt) {
    int total = cin * 343 * cop;
    for (int i = blockIdx.x * blockDim.x + threadIdx.x; i < total; i += gridDim.x * blockDim.x) {
        int co = i % cop;
        int rest = i / cop;  // ci*343 + tap
        float v = 0.f;
        if (co < cout) {
            int tap = rest % 343;
            int ci = rest / 343;
            v = w[(co * cin + ci) * 343 + tap];
        }
        wt[i] = v;
    }
}

// ---------------------------------------------------------------- fused direct conv
// Block: 256 threads = 8x8x4 voxels, each thread owns z and z+4 (T=2 planes).
// Per conceptual input channel ci: stage E^3 tile in LDS directly from the
// RAW previous conv output (Cst base channels), applying BN scale (+bias+relu
// for scalars) and computing tensor-square channels (a*sa)*(b*sb) on the fly.
// mode==0: plain read (layer 0, normalized x). Weights read thread-uniform
// from transposed [ci][tap][co] layout (scalar cache).
template <int COUT, int COP, int ST>
__global__ __launch_bounds__(256) void k_conv(
    const float* __restrict__ in, const float* __restrict__ wt, float* __restrict__ out,
    const float* __restrict__ scl, const float* __restrict__ bias,
    int B, int CIN, int Cst, int S, int Vc, int Sin, int Sout,
    int ntx, int nty, int cpc, int mode, int atomic_flag) {
    constexpr int E = 7 * ST + 7;
    __shared__ float tile[E * E * E];

    int t = blockIdx.x;
    int txb = t % ntx;
    int tyb = (t / ntx) % nty;
    int tzb = t / (ntx * nty);
    int b = blockIdx.y;
    int c0 = blockIdx.z * cpc;
    int c1 = min(CIN, c0 + cpc);
    int tid = threadIdx.x;
    int tx = tid & 7, ty = (tid >> 3) & 7, tzq = tid >> 6;

    float acc0[COUT], acc1[COUT];
#pragma unroll
    for (int i = 0; i < COUT; i++) { acc0[i] = 0.f; acc1[i] = 0.f; }

    int x0 = txb * 8 * ST - 3, y0 = tyb * 8 * ST - 3, z0 = tzb * 8 * ST - 3;
    int sp_in = Sin * Sin * Sin;

    for (int ci = c0; ci < c1; ++ci) {
        // --- wave-uniform channel decode ---
        int ca = ci, cb = 0, kind = 1;  // kind: 0 scalar(bias+relu) 1 vector(scale) 2 square
        float sa = 1.f, sb = 0.f, bv = 0.f;
        if (mode != 0) {
            int C = S + 3 * Vc;
            if (ci < S) {
                kind = 0; sa = scl[ci]; bv = bias[ci];
            } else if (ci < C) {
                kind = 1; sa = scl[ci];
            } else {
                int q = ci - C;
                int f = q / 9;
                int r = q - 9 * f;
                int i3 = r / 3;
                int j3 = r - 3 * i3;
                ca = S + 3 * f + i3;
                cb = S + 3 * f + j3;
                sa = scl[ca];
                sb = scl[cb];
                kind = 2;
            }
        }
        const float* pa = in + ((long long)b * Cst + ca) * sp_in;
        const float* pb = in + ((long long)b * Cst + cb) * sp_in;

        __syncthreads();  // protect prior-iteration LDS reads
        for (int idx = tid; idx < E * E * E; idx += 256) {
            int iz = idx / (E * E);
            int r = idx - iz * E * E;
            int iy = r / E;
            int ix = r - iy * E;
            int gx = x0 + ix, gy = y0 + iy, gz = z0 + iz;
            float v = 0.f;
            if ((unsigned)gx < (unsigned)Sin && (unsigned)gy < (unsigned)Sin &&
                (unsigned)gz < (unsigned)Sin) {
                int off = (gz * Sin + gy) * Sin + gx;
                float va = pa[off];
                if (kind == 0)
                    v = fmaxf(va * sa + bv, 0.f);
                else if (kind == 1)
                    v = va * sa;
                else
                    v = (va * sa) * (pb[off] * sb);
            }
            tile[idx] = v;
        }
        __syncthreads();

        const float* wci = wt + (long long)ci * 343 * COP;
#pragma unroll 1
        for (int kz = 0; kz < 7; ++kz) {
#pragma unroll 1
            for (int ky = 0; ky < 7; ++ky) {
                int r0 = ((tzq * ST + kz) * E + (ty * ST + ky)) * E + tx * ST;
                int r1 = r0 + 4 * ST * E * E;
                const float* wrow = wci + (kz * 7 + ky) * 7 * COP;
#pragma unroll
                for (int kx = 0; kx < 7; ++kx) {
                    float v0 = tile[r0 + kx];
                    float v1 = tile[r1 + kx];
                    const float* wp = wrow + kx * COP;
#pragma unroll
                    for (int co = 0; co < COUT; ++co) {
                        float w = wp[co];
                        acc0[co] = fmaf(w, v0, acc0[co]);
                        acc1[co] = fmaf(w, v1, acc1[co]);
                    }
                }
            }
        }
    }

    int ox = txb * 8 + tx, oy = tyb * 8 + ty;
    int oz0 = tzb * 8 + tzq, oz1 = oz0 + 4;
    if (ox >= Sout || oy >= Sout) return;
    int sp = Sout * Sout * Sout;
    long long obase = (long long)b * COUT * sp;
    int p0 = (oz0 * Sout + oy) * Sout + ox;
    int p1 = (oz1 * Sout + oy) * Sout + ox;
    if (atomic_flag) {
#pragma unroll
        for (int co = 0; co < COUT; co++) {
            if (oz0 < Sout) atomicAdd(&out[obase + (long long)co * sp + p0], acc0[co]);
            if (oz1 < Sout) atomicAdd(&out[obase + (long long)co * sp + p1], acc1[co]);
        }
    } else {
#pragma unroll
        for (int co = 0; co < COUT; co++) {
            if (oz0 < Sout) out[obase + (long long)co * sp + p0] = acc0[co];
            if (oz1 < Sout) out[obase + (long long)co * sp + p1] = acc1[co];
        }
    }
}

// ---------------------------------------------------------------- SE(3) BN stats
__global__ void k_sumsq(const float* __restrict__ y, int B, int C, int sp,
                        float* __restrict__ ssq) {
    int c = blockIdx.y;
    float s = 0.f;
    int n = B * sp;
    for (int e = blockIdx.x * blockDim.x + threadIdx.x; e < n; e += gridDim.x * blockDim.x) {
        int b = e / sp;
        int p = e - b * sp;
        float v = y[((long long)b * C + c) * sp + p];
        s += v * v;
    }
    s = waveReduceSum(s);
    __shared__ float sh[4];
    int lane = threadIdx.x & 63, w = threadIdx.x >> 6;
    if (lane == 0) sh[w] = s;
    __syncthreads();
    if (threadIdx.x == 0) {
        float a = 0.f;
        int nw = blockDim.x >> 6;
        for (int i = 0; i < nw; i++) a += sh[i];
        atomicAdd(&ssq[c], a);
    }
}

__global__ void k_scales(const float* __restrict__ ssq, const float* __restrict__ bnw,
                         int s, int v, float invN, float* __restrict__ scale) {
    int t = threadIdx.x;
    if (t < s) {
        float n = ssq[t] * invN;
        scale[t] = bnw[t] * rsqrtf(n + EPSF);
    }
    if (t < v) {
        float n = (ssq[s + 3 * t] + ssq[s + 3 * t + 1] + ssq[s + 3 * t + 2]) * invN * (1.f / 3.f);
        float sc = bnw[s + t] * rsqrtf(n + EPSF);
        scale[s + 3 * t] = sc;
        scale[s + 3 * t + 1] = sc;
        scale[s + 3 * t + 2] = sc;
    }
}

// layer 6 BN scale + spatial mean + batch norm + affine -> (32,10)
__global__ void k_final(const float* __restrict__ y, const float* __restrict__ scale,
                        const float* __restrict__ gamma, const float* __restrict__ beta,
                        float* __restrict__ out) {
    __shared__ float m[320];
    __shared__ float mu[10], isd[10];
    int t = threadIdx.x;
    if (t < 320) {
        int b = t / 10, c = t % 10;
        const float* yp = y + (b * 10 + c) * 64;
        float s = 0.f;
        for (int p = 0; p < 64; p++) s += yp[p];
        m[t] = s * (1.f / 64.f) * scale[c];
    }
    __syncthreads();
    if (t < 10) {
        float a = 0.f, a2 = 0.f;
        for (int b = 0; b < 32; b++) {
            float vv = m[b * 10 + t];
            a += vv;
            a2 += vv * vv;
        }
        a *= (1.f / 32.f);
        a2 = a2 * (1.f / 32.f) - a * a;
        mu[t] = a;
        isd[t] = rsqrtf(a2 + EPSF);
    }
    __syncthreads();
    if (t < 320) {
        int c = t % 10;
        out[t] = (m[t] - mu[c]) * isd[c] * gamma[c] + beta[c];
    }
}

// ---------------------------------------------------------------- driver
extern "C" void kernel_launch(void* const* d_in, const int* in_sizes, int n_in,
                              void* d_out, int out_size, void* d_ws, size_t ws_size,
                              hipStream_t stream) {
    // Diagnostic guard: if workspace too small, emit zeros (absmax ~= 2.796)
    // instead of faulting, so the failure mode is identifiable.
    if (ws_size < (size_t)WS_NEED) {
        k_zero_out<<<1, 256, 0, stream>>>((float*)d_out, out_size);
        return;
    }

    const float* x = (const float*)d_in[0];

    // dict order: x, (w_i, bnw_i) x7, b0..b5, gamma, beta
    int iw[7], ibnw[7], ibias[6];
    if (in_sizes[2] == 6) {
        for (int i = 0; i < 7; i++) { iw[i] = 1 + 2 * i; ibnw[i] = 2 + 2 * i; }
    } else {
        for (int i = 0; i < 7; i++) { iw[i] = 1 + i; ibnw[i] = 8 + i; }
    }
    for (int i = 0; i < 6; i++) ibias[i] = 15 + i;
    const float* gamma = (const float*)d_in[21];
    const float* beta = (const float*)d_in[22];

    char* ws = (char*)d_ws;
    float* rodd = (float*)(ws + ODD_OFF);    // X_norm, Y1, Y3, Y5
    float* reven = (float*)(ws + EVEN_OFF);  // Y0, Y2, Y4, Y6
    float* wtall = (float*)(ws + WT_OFF);
    float* stats = (float*)(ws + STATS_OFF);

    hipMemsetAsync(stats, 0, 1024 * sizeof(float), stream);

    const int nIn = 32 * 64 * 64 * 64;
    k_input_stats<<<2048, 256, 0, stream>>>(x, nIn, stats);
    k_normalize<<<2048, 256, 0, stream>>>(x, nIn, 1.0f / (float)nIn, stats, rodd);

    // per-layer tables
    static const int cinA[7] = {1, 28, 70, 70, 84, 84, 98};   // conceptual (with squares)
    static const int coutA[7] = {10, 25, 25, 30, 30, 35, 10};
    static const int copA[7] = {12, 28, 28, 32, 32, 36, 12};
    static const int sA[7] = {4, 10, 10, 12, 12, 14, 10};     // FEATURES[i+1]
    static const int vA[7] = {2, 5, 5, 6, 6, 7, 0};
    static const int SinA[7] = {64, 32, 32, 16, 16, 8, 8};
    static const int SoutA[7] = {32, 32, 16, 16, 8, 8, 4};
    static const int ntxA[7] = {4, 4, 2, 2, 1, 1, 1};
    static const int chA[7] = {1, 1, 8, 8, 28, 28, 49};
    static const long long wtoffA[7] = {0, 4116, 273028, 945308, 1713628, 2635612, 3672844};
    // input base-channel counts (stored channels of previous output)
    static const int cstA[7] = {1, 10, 25, 25, 30, 30, 35};

    for (int i = 0; i < 7; i++) {
        int total = cinA[i] * 343 * copA[i];
        int g = (total + 255) / 256;
        if (g > 1024) g = 1024;
        k_wtrans<<<g, 256, 0, stream>>>((const float*)d_in[iw[i]], coutA[i], cinA[i], copA[i],
                                        wtall + wtoffA[i]);
    }

    for (int i = 0; i < 7; i++) {
        int sp = SoutA[i] * SoutA[i] * SoutA[i];
        int cpc = (cinA[i] + chA[i] - 1) / chA[i];
        int atom = (chA[i] > 1) ? 1 : 0;
        float* Yin = (i == 0) ? rodd : ((i & 1) ? reven : rodd);   // input of layer i = Y_{i-1}
        float* Yout = (i & 1) ? rodd : reven;                      // Y0->even, Y1->odd, ...
        const float* scl_in = (i == 0) ? nullptr : (stats + 16 + (i - 1) * 128 + 64);
        const float* bias_in = (i == 0) ? nullptr : (const float*)d_in[ibias[i - 1]];
        int mode = (i == 0) ? 0 : 1;
        int S_in = (i == 0) ? 1 : sA[i - 1];
        int V_in = (i == 0) ? 0 : vA[i - 1];

        if (atom) hipMemsetAsync(Yout, 0, (size_t)32 * coutA[i] * sp * 4, stream);
        dim3 g(ntxA[i] * ntxA[i] * ntxA[i], 32, chA[i]);
        const float* wtb = wtall + wtoffA[i];
        switch (i) {
            case 0: k_conv<10, 12, 2><<<g, 256, 0, stream>>>(Yin, wtb, Yout, scl_in, bias_in, 32, cinA[i], cstA[i], S_in, V_in, SinA[i], SoutA[i], ntxA[i], ntxA[i], cpc, mode, atom); break;
            case 1: k_conv<25, 28, 1><<<g, 256, 0, stream>>>(Yin, wtb, Yout, scl_in, bias_in, 32, cinA[i], cstA[i], S_in, V_in, SinA[i], SoutA[i], ntxA[i], ntxA[i], cpc, mode, atom); break;
            case 2: k_conv<25, 28, 2><<<g, 256, 0, stream>>>(Yin, wtb, Yout, scl_in, bias_in, 32, cinA[i], cstA[i], S_in, V_in, SinA[i], SoutA[i], ntxA[i], ntxA[i], cpc, mode, atom); break;
            case 3: k_conv<30, 32, 1><<<g, 256, 0, stream>>>(Yin, wtb, Yout, scl_in, bias_in, 32, cinA[i], cstA[i], S_in, V_in, SinA[i], SoutA[i], ntxA[i], ntxA[i], cpc, mode, atom); break;
            case 4: k_conv<30, 32, 2><<<g, 256, 0, stream>>>(Yin, wtb, Yout, scl_in, bias_in, 32, cinA[i], cstA[i], S_in, V_in, SinA[i], SoutA[i], ntxA[i], ntxA[i], cpc, mode, atom); break;
            case 5: k_conv<35, 36, 1><<<g, 256, 0, stream>>>(Yin, wtb, Yout, scl_in, bias_in, 32, cinA[i], cstA[i], S_in, V_in, SinA[i], SoutA[i], ntxA[i], ntxA[i], cpc, mode, atom); break;
            case 6: k_conv<10, 12, 2><<<g, 256, 0, stream>>>(Yin, wtb, Yout, scl_in, bias_in, 32, cinA[i], cstA[i], S_in, V_in, SinA[i], SoutA[i], ntxA[i], ntxA[i], cpc, mode, atom); break;
        }

        float* ssq = stats + 16 + i * 128;
        float* scl = ssq + 64;
        int n = 32 * sp;
        int nblk = (n + 255) / 256;
        if (nblk > 256) nblk = 256;
        k_sumsq<<<dim3(nblk, coutA[i]), 256, 0, stream>>>(Yout, 32, coutA[i], sp, ssq);
        k_scales<<<1, 64, 0, stream>>>(ssq, (const float*)d_in[ibnw[i]], sA[i], vA[i],
                                       1.0f / (float)(32 * sp), scl);
    }

    float* scl6 = stats + 16 + 6 * 128 + 64;
    k_final<<<1, 512, 0, stream>>>(reven, scl6, gamma, beta, (float*)d_out);
}

// Round 9
// 6655.212 us; speedup vs baseline: 1.6279x; 1.6279x over previous
//
#include <hip/hip_runtime.h>

#define EPSF 1e-5f

// workspace layout (bytes)
#define ODD_OFF   0LL                  // X_norm, Y1, Y3, Y5 (max 104,857,600)
#define EVEN_OFF  104857600LL          // Y0, Y2, Y4, Y6     (max 41,943,040)
#define WT_OFF    146800640LL          // transposed weights (16,304,848)
#define STATS_OFF 163105488LL          // stats/scales (1024 floats)
#define WS_NEED   163110000LL

typedef short bf16x8 __attribute__((ext_vector_type(8)));
typedef float f32x16 __attribute__((ext_vector_type(16)));

__device__ __forceinline__ ushort f2bf(float f) {
    unsigned u = __float_as_uint(f);
    u += 0x7FFF + ((u >> 16) & 1);   // round-to-nearest-even
    return (ushort)(u >> 16);
}
__device__ __forceinline__ unsigned pk(float a, float b) {
    return (unsigned)f2bf(a) | ((unsigned)f2bf(b) << 16);
}

// ---------------------------------------------------------------- utility
__global__ void k_zero_out(float* __restrict__ out, int n) {
    for (int i = blockIdx.x * blockDim.x + threadIdx.x; i < n; i += gridDim.x * blockDim.x)
        out[i] = 0.f;
}

__device__ __forceinline__ float waveReduceSum(float v) {
    v += __shfl_down(v, 32);
    v += __shfl_down(v, 16);
    v += __shfl_down(v, 8);
    v += __shfl_down(v, 4);
    v += __shfl_down(v, 2);
    v += __shfl_down(v, 1);
    return v;
}

__global__ void k_input_stats(const float* __restrict__ x, int n, float* __restrict__ stats) {
    float s = 0.f, s2 = 0.f;
    for (int i = blockIdx.x * blockDim.x + threadIdx.x; i < n; i += gridDim.x * blockDim.x) {
        float v = x[i];
        s += v;
        s2 += v * v;
    }
    __shared__ float sh0[4], sh1[4];
    s = waveReduceSum(s);
    s2 = waveReduceSum(s2);
    int lane = threadIdx.x & 63, w = threadIdx.x >> 6;
    if (lane == 0) { sh0[w] = s; sh1[w] = s2; }
    __syncthreads();
    if (threadIdx.x == 0) {
        float a = 0.f, b = 0.f;
        int nw = blockDim.x >> 6;
        for (int i = 0; i < nw; i++) { a += sh0[i]; b += sh1[i]; }
        atomicAdd(&stats[0], a);
        atomicAdd(&stats[1], b);
    }
}

__global__ void k_normalize(const float* __restrict__ x, int n, float invn,
                            const float* __restrict__ stats, float* __restrict__ y) {
    float mu = stats[0] * invn;
    float var = stats[1] * invn - mu * mu;
    float sc = rsqrtf(var + EPSF);
    for (int i = blockIdx.x * blockDim.x + threadIdx.x; i < n; i += gridDim.x * blockDim.x)
        y[i] = (x[i] - mu) * sc;
}

// w[co][ci][tap] -> wt[(ci*343+tap)*cop + co]  (pad co to cop with zeros)
__global__ void k_wtrans(const float* __restrict__ w, int cout, int cin, int cop,
                         float* __restrict__ wt) {
    int total = cin * 343 * cop;
    for (int i = blockIdx.x * blockDim.x + threadIdx.x; i < total; i += gridDim.x * blockDim.x) {
        int co = i % cop;
        int rest = i / cop;  // ci*343 + tap
        float v = 0.f;
        if (co < cout) {
            int tap = rest % 343;
            int ci = rest / 343;
            v = w[(co * cin + ci) * 343 + tap];
        }
        wt[i] = v;
    }
}

// layer-1 bf16 weights: wt2[tap][cig(2)][co(32)][ci(16)], co>=25 / ci>=28 zero
__global__ void k_wtrans2(const float* __restrict__ w1, ushort* __restrict__ wt2) {
    int i = blockIdx.x * blockDim.x + threadIdx.x;  // 343*2*32*16 = 351232
    if (i >= 351232) return;
    int cil = i & 15, co = (i >> 4) & 31, cig = (i >> 9) & 1, tap = i >> 10;
    int ci = cig * 16 + cil;
    float v = 0.f;
    if (co < 25 && ci < 28) v = w1[(co * 28 + ci) * 343 + tap];
    wt2[i] = f2bf(v);
}

// ---------------------------------------------------------------- L1 MFMA conv
// stride-1, Sin=Sout=32, cin 28->32 (BN/bias/relu/squares fused in staging),
// cout 25->32. Block = 256 thr = 4 waves; out-tile 8x8x4 (x,y,z); wave w owns
// z-plane w as 2 M-tiles of 32 voxels (y-halves). K-step = 16 ci.
// LDS halo tile [z=10][y=14][x=14][ci=16] bf16, OOB-zeroed (no tap masking).
__global__ __launch_bounds__(256) void k_mfma_l1(
    const float* __restrict__ y0, const ushort* __restrict__ wt2, float* __restrict__ y1,
    const float* __restrict__ scl, const float* __restrict__ bias) {
    __shared__ __align__(16) ushort tile[10 * 14 * 14 * 16];

    int tid = threadIdx.x;
    int l = tid & 63, w = tid >> 6;
    int tb = blockIdx.x;
    int x0 = (tb & 3) * 8, y0c = ((tb >> 2) & 3) * 8, z0 = (tb >> 4) * 4;
    int b = blockIdx.y;

    int co = l & 31, h = l >> 5, xl = l & 7, yl = (l >> 3) & 3;

    const float sc0 = scl[0], sc1 = scl[1], sc2 = scl[2], sc3 = scl[3];
    const float sc4 = scl[4], sc5 = scl[5], sc6 = scl[6], sc7 = scl[7];
    const float sc8 = scl[8], sc9 = scl[9];
    const float bb0 = bias[0], bb1 = bias[1], bb2 = bias[2], bb3 = bias[3];

    f32x16 acc0 = {}, acc1 = {};
    const float* yb = y0 + (long long)b * 10 * 32768;

#pragma unroll
    for (int cig = 0; cig < 2; ++cig) {
        __syncthreads();  // protect previous-iteration LDS reads
        // ---- stage halo tile: 1960 voxels x 16 ci (fused BN/bias/relu/squares)
        for (int idx = tid; idx < 1960; idx += 256) {
            int vz = idx / 196, r = idx - vz * 196;
            int vy = r / 14, vx = r - vy * 14;
            int gz = z0 - 3 + vz, gy = y0c - 3 + vy, gx = x0 - 3 + vx;
            bool inb = (unsigned)gx < 32u && (unsigned)gy < 32u && (unsigned)gz < 32u;
            int off = (gz * 32 + gy) * 32 + gx;
            const float* yv = yb + off;
            float sv0 = (inb ? yv[4 * 32768] : 0.f) * sc4;
            float sv1 = (inb ? yv[5 * 32768] : 0.f) * sc5;
            float sv2 = (inb ? yv[6 * 32768] : 0.f) * sc6;
            float sv3 = (inb ? yv[7 * 32768] : 0.f) * sc7;
            float sv4 = (inb ? yv[8 * 32768] : 0.f) * sc8;
            float sv5 = (inb ? yv[9 * 32768] : 0.f) * sc9;
            unsigned p0, p1, p2, p3, p4, p5, p6, p7;
            if (cig == 0) {
                float c0 = inb ? yv[0] : 0.f;
                float c1 = inb ? yv[1 * 32768] : 0.f;
                float c2 = inb ? yv[2 * 32768] : 0.f;
                float c3 = inb ? yv[3 * 32768] : 0.f;
                float r0 = fmaxf(c0 * sc0 + bb0, 0.f);
                float r1 = fmaxf(c1 * sc1 + bb1, 0.f);
                float r2 = fmaxf(c2 * sc2 + bb2, 0.f);
                float r3 = fmaxf(c3 * sc3 + bb3, 0.f);
                p0 = pk(r0, r1);
                p1 = pk(r2, r3);
                p2 = pk(sv0, sv1);
                p3 = pk(sv2, sv3);
                p4 = pk(sv4, sv5);
                p5 = pk(sv0 * sv0, sv0 * sv1);
                p6 = pk(sv0 * sv2, sv1 * sv0);
                p7 = pk(sv1 * sv1, sv1 * sv2);
            } else {
                p0 = pk(sv2 * sv0, sv2 * sv1);
                p1 = pk(sv2 * sv2, sv3 * sv3);
                p2 = pk(sv3 * sv4, sv3 * sv5);
                p3 = pk(sv4 * sv3, sv4 * sv4);
                p4 = pk(sv4 * sv5, sv5 * sv3);
                p5 = pk(sv5 * sv4, sv5 * sv5);
                p6 = 0u;
                p7 = 0u;
            }
            ushort* dst = &tile[idx * 16];
            ((uint4*)dst)[0] = make_uint4(p0, p1, p2, p3);
            ((uint4*)dst)[1] = make_uint4(p4, p5, p6, p7);
        }
        __syncthreads();

        // ---- tap loop: per (kz,ky,kx): 2 A ds_reads + 1 B global load + 2 MFMA
        const ushort* wb = wt2 + cig * 512 + co * 16 + h * 8;
#pragma unroll 1
        for (int kz = 0; kz < 7; ++kz) {
#pragma unroll 1
            for (int ky = 0; ky < 7; ++ky) {
                int vb = ((w + kz) * 14 + (yl + ky)) * 14 + xl;
                const ushort* ap = &tile[vb * 16 + h * 8];
                const ushort* wp = wb + (kz * 7 + ky) * 7 * 1024;
#pragma unroll
                for (int kx = 0; kx < 7; ++kx) {
                    bf16x8 a0 = *(const bf16x8*)(ap + kx * 16);
                    bf16x8 a1 = *(const bf16x8*)(ap + kx * 16 + 4 * 14 * 16);
                    bf16x8 bf = *(const bf16x8*)(wp + kx * 1024);
                    acc0 = __builtin_amdgcn_mfma_f32_32x32x16_bf16(a0, bf, acc0, 0, 0, 0);
                    acc1 = __builtin_amdgcn_mfma_f32_32x32x16_bf16(a1, bf, acc1, 0, 0, 0);
                }
            }
        }
    }

    // ---- epilogue: C/D layout col=lane&31(co), row=(reg&3)+8*(reg>>2)+4*(lane>>5)
    if (co < 25) {
        float* outp = y1 + ((long long)b * 25 + co) * 32768;
        int zz = z0 + w;
#pragma unroll
        for (int r = 0; r < 16; ++r) {
            int m = (r & 3) + 8 * (r >> 2) + 4 * h;
            int xx = x0 + (m & 7);
            int yy = y0c + (m >> 3);
            outp[(zz * 32 + yy) * 32 + xx] = acc0[r];
            outp[(zz * 32 + yy + 4) * 32 + xx] = acc1[r];
        }
    }
}

// ---------------------------------------------------------------- fused direct conv (fp32)
template <int COUT, int COP, int ST>
__global__ __launch_bounds__(256) void k_conv(
    const float* __restrict__ in, const float* __restrict__ wt, float* __restrict__ out,
    const float* __restrict__ scl, const float* __restrict__ bias,
    int B, int CIN, int Cst, int S, int Vc, int Sin, int Sout,
    int ntx, int nty, int cpc, int mode, int atomic_flag) {
    constexpr int E = 7 * ST + 7;
    __shared__ float tile[E * E * E];

    int t = blockIdx.x;
    int txb = t % ntx;
    int tyb = (t / ntx) % nty;
    int tzb = t / (ntx * nty);
    int b = blockIdx.y;
    int c0 = blockIdx.z * cpc;
    int c1 = min(CIN, c0 + cpc);
    int tid = threadIdx.x;
    int tx = tid & 7, ty = (tid >> 3) & 7, tzq = tid >> 6;

    float acc0[COUT], acc1[COUT];
#pragma unroll
    for (int i = 0; i < COUT; i++) { acc0[i] = 0.f; acc1[i] = 0.f; }

    int x0 = txb * 8 * ST - 3, y0 = tyb * 8 * ST - 3, z0 = tzb * 8 * ST - 3;
    int sp_in = Sin * Sin * Sin;

    for (int ci = c0; ci < c1; ++ci) {
        int ca = ci, cb = 0, kind = 1;
        float sa = 1.f, sb = 0.f, bv = 0.f;
        if (mode != 0) {
            int C = S + 3 * Vc;
            if (ci < S) {
                kind = 0; sa = scl[ci]; bv = bias[ci];
            } else if (ci < C) {
                kind = 1; sa = scl[ci];
            } else {
                int q = ci - C;
                int f = q / 9;
                int r = q - 9 * f;
                int i3 = r / 3;
                int j3 = r - 3 * i3;
                ca = S + 3 * f + i3;
                cb = S + 3 * f + j3;
                sa = scl[ca];
                sb = scl[cb];
                kind = 2;
            }
        }
        const float* pa = in + ((long long)b * Cst + ca) * sp_in;
        const float* pb = in + ((long long)b * Cst + cb) * sp_in;

        __syncthreads();
        for (int idx = tid; idx < E * E * E; idx += 256) {
            int iz = idx / (E * E);
            int r = idx - iz * E * E;
            int iy = r / E;
            int ix = r - iy * E;
            int gx = x0 + ix, gy = y0 + iy, gz = z0 + iz;
            float v = 0.f;
            if ((unsigned)gx < (unsigned)Sin && (unsigned)gy < (unsigned)Sin &&
                (unsigned)gz < (unsigned)Sin) {
                int off = (gz * Sin + gy) * Sin + gx;
                float va = pa[off];
                if (kind == 0)
                    v = fmaxf(va * sa + bv, 0.f);
                else if (kind == 1)
                    v = va * sa;
                else
                    v = (va * sa) * (pb[off] * sb);
            }
            tile[idx] = v;
        }
        __syncthreads();

        const float* wci = wt + (long long)ci * 343 * COP;
#pragma unroll 1
        for (int kz = 0; kz < 7; ++kz) {
#pragma unroll 1
            for (int ky = 0; ky < 7; ++ky) {
                int r0 = ((tzq * ST + kz) * E + (ty * ST + ky)) * E + tx * ST;
                int r1 = r0 + 4 * ST * E * E;
                const float* wrow = wci + (kz * 7 + ky) * 7 * COP;
#pragma unroll
                for (int kx = 0; kx < 7; ++kx) {
                    float v0 = tile[r0 + kx];
                    float v1 = tile[r1 + kx];
                    const float* wp = wrow + kx * COP;
#pragma unroll
                    for (int co = 0; co < COUT; ++co) {
                        float w = wp[co];
                        acc0[co] = fmaf(w, v0, acc0[co]);
                        acc1[co] = fmaf(w, v1, acc1[co]);
                    }
                }
            }
        }
    }

    int ox = txb * 8 + tx, oy = tyb * 8 + ty;
    int oz0 = tzb * 8 + tzq, oz1 = oz0 + 4;
    if (ox >= Sout || oy >= Sout) return;
    int sp = Sout * Sout * Sout;
    long long obase = (long long)b * COUT * sp;
    int p0 = (oz0 * Sout + oy) * Sout + ox;
    int p1 = (oz1 * Sout + oy) * Sout + ox;
    if (atomic_flag) {
#pragma unroll
        for (int co = 0; co < COUT; co++) {
            if (oz0 < Sout) atomicAdd(&out[obase + (long long)co * sp + p0], acc0[co]);
            if (oz1 < Sout) atomicAdd(&out[obase + (long long)co * sp + p1], acc1[co]);
        }
    } else {
#pragma unroll
        for (int co = 0; co < COUT; co++) {
            if (oz0 < Sout) out[obase + (long long)co * sp + p0] = acc0[co];
            if (oz1 < Sout) out[obase + (long long)co * sp + p1] = acc1[co];
        }
    }
}

// ---------------------------------------------------------------- SE(3) BN stats
__global__ void k_sumsq(const float* __restrict__ y, int B, int C, int sp,
                        float* __restrict__ ssq) {
    int c = blockIdx.y;
    float s = 0.f;
    int n = B * sp;
    for (int e = blockIdx.x * blockDim.x + threadIdx.x; e < n; e += gridDim.x * blockDim.x) {
        int b = e / sp;
        int p = e - b * sp;
        float v = y[((long long)b * C + c) * sp + p];
        s += v * v;
    }
    s = waveReduceSum(s);
    __shared__ float sh[4];
    int lane = threadIdx.x & 63, w = threadIdx.x >> 6;
    if (lane == 0) sh[w] = s;
    __syncthreads();
    if (threadIdx.x == 0) {
        float a = 0.f;
        int nw = blockDim.x >> 6;
        for (int i = 0; i < nw; i++) a += sh[i];
        atomicAdd(&ssq[c], a);
    }
}

__global__ void k_scales(const float* __restrict__ ssq, const float* __restrict__ bnw,
                         int s, int v, float invN, float* __restrict__ scale) {
    int t = threadIdx.x;
    if (t < s) {
        float n = ssq[t] * invN;
        scale[t] = bnw[t] * rsqrtf(n + EPSF);
    }
    if (t < v) {
        float n = (ssq[s + 3 * t] + ssq[s + 3 * t + 1] + ssq[s + 3 * t + 2]) * invN * (1.f / 3.f);
        float sc = bnw[s + t] * rsqrtf(n + EPSF);
        scale[s + 3 * t] = sc;
        scale[s + 3 * t + 1] = sc;
        scale[s + 3 * t + 2] = sc;
    }
}

// layer 6 BN scale + spatial mean + batch norm + affine -> (32,10)
__global__ void k_final(const float* __restrict__ y, const float* __restrict__ scale,
                        const float* __restrict__ gamma, const float* __restrict__ beta,
                        float* __restrict__ out) {
    __shared__ float m[320];
    __shared__ float mu[10], isd[10];
    int t = threadIdx.x;
    if (t < 320) {
        int b = t / 10, c = t % 10;
        const float* yp = y + (b * 10 + c) * 64;
        float s = 0.f;
        for (int p = 0; p < 64; p++) s += yp[p];
        m[t] = s * (1.f / 64.f) * scale[c];
    }
    __syncthreads();
    if (t < 10) {
        float a = 0.f, a2 = 0.f;
        for (int b = 0; b < 32; b++) {
            float vv = m[b * 10 + t];
            a += vv;
            a2 += vv * vv;
        }
        a *= (1.f / 32.f);
        a2 = a2 * (1.f / 32.f) - a * a;
        mu[t] = a;
        isd[t] = rsqrtf(a2 + EPSF);
    }
    __syncthreads();
    if (t < 320) {
        int c = t % 10;
        out[t] = (m[t] - mu[c]) * isd[c] * gamma[c] + beta[c];
    }
}

// ---------------------------------------------------------------- driver
extern "C" void kernel_launch(void* const* d_in, const int* in_sizes, int n_in,
                              void* d_out, int out_size, void* d_ws, size_t ws_size,
                              hipStream_t stream) {
    if (ws_size < (size_t)WS_NEED) {
        k_zero_out<<<1, 256, 0, stream>>>((float*)d_out, out_size);
        return;
    }

    const float* x = (const float*)d_in[0];

    int iw[7], ibnw[7], ibias[6];
    if (in_sizes[2] == 6) {
        for (int i = 0; i < 7; i++) { iw[i] = 1 + 2 * i; ibnw[i] = 2 + 2 * i; }
    } else {
        for (int i = 0; i < 7; i++) { iw[i] = 1 + i; ibnw[i] = 8 + i; }
    }
    for (int i = 0; i < 6; i++) ibias[i] = 15 + i;
    const float* gamma = (const float*)d_in[21];
    const float* beta = (const float*)d_in[22];

    char* ws = (char*)d_ws;
    float* rodd = (float*)(ws + ODD_OFF);    // X_norm, Y1, Y3, Y5
    float* reven = (float*)(ws + EVEN_OFF);  // Y0, Y2, Y4, Y6
    float* wtall = (float*)(ws + WT_OFF);
    float* stats = (float*)(ws + STATS_OFF);
    // layer-1 bf16 weights reuse layer-1's (now unused) fp32 slot [4116, 273028)
    ushort* wt2 = (ushort*)(wtall + 4116);

    hipMemsetAsync(stats, 0, 1024 * sizeof(float), stream);

    const int nIn = 32 * 64 * 64 * 64;
    k_input_stats<<<2048, 256, 0, stream>>>(x, nIn, stats);
    k_normalize<<<2048, 256, 0, stream>>>(x, nIn, 1.0f / (float)nIn, stats, rodd);

    static const int cinA[7] = {1, 28, 70, 70, 84, 84, 98};
    static const int coutA[7] = {10, 25, 25, 30, 30, 35, 10};
    static const int copA[7] = {12, 28, 28, 32, 32, 36, 12};
    static const int sA[7] = {4, 10, 10, 12, 12, 14, 10};
    static const int vA[7] = {2, 5, 5, 6, 6, 7, 0};
    static const int SinA[7] = {64, 32, 32, 16, 16, 8, 8};
    static const int SoutA[7] = {32, 32, 16, 16, 8, 8, 4};
    static const int ntxA[7] = {4, 4, 2, 2, 1, 1, 1};
    static const int chA[7] = {1, 1, 8, 8, 28, 28, 49};
    static const long long wtoffA[7] = {0, 4116, 273028, 945308, 1713628, 2635612, 3672844};
    static const int cstA[7] = {1, 10, 25, 25, 30, 30, 35};

    for (int i = 0; i < 7; i++) {
        if (i == 1) continue;  // layer 1 uses bf16 weights
        int total = cinA[i] * 343 * copA[i];
        int g = (total + 255) / 256;
        if (g > 1024) g = 1024;
        k_wtrans<<<g, 256, 0, stream>>>((const float*)d_in[iw[i]], coutA[i], cinA[i], copA[i],
                                        wtall + wtoffA[i]);
    }
    k_wtrans2<<<1372, 256, 0, stream>>>((const float*)d_in[iw[1]], wt2);

    for (int i = 0; i < 7; i++) {
        int sp = SoutA[i] * SoutA[i] * SoutA[i];
        int cpc = (cinA[i] + chA[i] - 1) / chA[i];
        int atom = (chA[i] > 1) ? 1 : 0;
        float* Yin = (i == 0) ? rodd : ((i & 1) ? reven : rodd);
        float* Yout = (i & 1) ? rodd : reven;
        const float* scl_in = (i == 0) ? nullptr : (stats + 16 + (i - 1) * 128 + 64);
        const float* bias_in = (i == 0) ? nullptr : (const float*)d_in[ibias[i - 1]];
        int mode = (i == 0) ? 0 : 1;
        int S_in = (i == 0) ? 1 : sA[i - 1];
        int V_in = (i == 0) ? 0 : vA[i - 1];

        if (atom) hipMemsetAsync(Yout, 0, (size_t)32 * coutA[i] * sp * 4, stream);
        dim3 g(ntxA[i] * ntxA[i] * ntxA[i], 32, chA[i]);
        const float* wtb = wtall + wtoffA[i];
        switch (i) {
            case 0: k_conv<10, 12, 2><<<g, 256, 0, stream>>>(Yin, wtb, Yout, scl_in, bias_in, 32, cinA[i], cstA[i], S_in, V_in, SinA[i], SoutA[i], ntxA[i], ntxA[i], cpc, mode, atom); break;
            case 1:
                k_mfma_l1<<<dim3(128, 32), 256, 0, stream>>>(Yin, wt2, Yout, scl_in, bias_in);
                break;
            case 2: k_conv<25, 28, 2><<<g, 256, 0, stream>>>(Yin, wtb, Yout, scl_in, bias_in, 32, cinA[i], cstA[i], S_in, V_in, SinA[i], SoutA[i], ntxA[i], ntxA[i], cpc, mode, atom); break;
            case 3: k_conv<30, 32, 1><<<g, 256, 0, stream>>>(Yin, wtb, Yout, scl_in, bias_in, 32, cinA[i], cstA[i], S_in, V_in, SinA[i], SoutA[i], ntxA[i], ntxA[i], cpc, mode, atom); break;
            case 4: k_conv<30, 32, 2><<<g, 256, 0, stream>>>(Yin, wtb, Yout, scl_in, bias_in, 32, cinA[i], cstA[i], S_in, V_in, SinA[i], SoutA[i], ntxA[i], ntxA[i], cpc, mode, atom); break;
            case 5: k_conv<35, 36, 1><<<g, 256, 0, stream>>>(Yin, wtb, Yout, scl_in, bias_in, 32, cinA[i], cstA[i], S_in, V_in, SinA[i], SoutA[i], ntxA[i], ntxA[i], cpc, mode, atom); break;
            case 6: k_conv<10, 12, 2><<<g, 256, 0, stream>>>(Yin, wtb, Yout, scl_in, bias_in, 32, cinA[i], cstA[i], S_in, V_in, SinA[i], SoutA[i], ntxA[i], ntxA[i], cpc, mode, atom); break;
        }

        float* ssq = stats + 16 + i * 128;
        float* scl = ssq + 64;
        int n = 32 * sp;
        int nblk = (n + 255) / 256;
        if (nblk > 256) nblk = 256;
        k_sumsq<<<dim3(nblk, coutA[i]), 256, 0, stream>>>(Yout, 32, coutA[i], sp, ssq);
        k_scales<<<1, 64, 0, stream>>>(ssq, (const float*)d_in[ibnw[i]], sA[i], vA[i],
                                       1.0f / (float)(32 * sp), scl);
    }

    float* scl6 = stats + 16 + 6 * 128 + 64;
    k_final<<<1, 512, 0, stream>>>(reven, scl6, gamma, beta, (float*)d_out);
}

// Round 10
// 5682.114 us; speedup vs baseline: 1.9067x; 1.1713x over previous
//
#include <hip/hip_runtime.h>

#define EPSF 1e-5f

// workspace layout (bytes)
#define ODD_OFF   0LL                  // X_norm, Y1, Y3, Y5 (max 104,857,600)
#define EVEN_OFF  104857600LL          // Y0, Y2, Y4, Y6     (max 41,943,040)
#define WT_OFF    146800640LL          // transposed weights (16,304,848)
#define STATS_OFF 163105488LL          // stats/scales (1024 floats)
#define WS_NEED   163110000LL

typedef _Float16 f16x8 __attribute__((ext_vector_type(8)));
typedef float f32x16 __attribute__((ext_vector_type(16)));

__device__ __forceinline__ ushort f2h(float f) {
    return __builtin_bit_cast(ushort, (_Float16)f);
}
__device__ __forceinline__ unsigned pkh(float a, float b) {
    return (unsigned)f2h(a) | ((unsigned)f2h(b) << 16);
}

// ---------------------------------------------------------------- utility
__global__ void k_zero_out(float* __restrict__ out, int n) {
    for (int i = blockIdx.x * blockDim.x + threadIdx.x; i < n; i += gridDim.x * blockDim.x)
        out[i] = 0.f;
}

__device__ __forceinline__ float waveReduceSum(float v) {
    v += __shfl_down(v, 32);
    v += __shfl_down(v, 16);
    v += __shfl_down(v, 8);
    v += __shfl_down(v, 4);
    v += __shfl_down(v, 2);
    v += __shfl_down(v, 1);
    return v;
}

__global__ void k_input_stats(const float* __restrict__ x, int n, float* __restrict__ stats) {
    float s = 0.f, s2 = 0.f;
    for (int i = blockIdx.x * blockDim.x + threadIdx.x; i < n; i += gridDim.x * blockDim.x) {
        float v = x[i];
        s += v;
        s2 += v * v;
    }
    __shared__ float sh0[4], sh1[4];
    s = waveReduceSum(s);
    s2 = waveReduceSum(s2);
    int lane = threadIdx.x & 63, w = threadIdx.x >> 6;
    if (lane == 0) { sh0[w] = s; sh1[w] = s2; }
    __syncthreads();
    if (threadIdx.x == 0) {
        float a = 0.f, b = 0.f;
        int nw = blockDim.x >> 6;
        for (int i = 0; i < nw; i++) { a += sh0[i]; b += sh1[i]; }
        atomicAdd(&stats[0], a);
        atomicAdd(&stats[1], b);
    }
}

__global__ void k_normalize(const float* __restrict__ x, int n, float invn,
                            const float* __restrict__ stats, float* __restrict__ y) {
    float mu = stats[0] * invn;
    float var = stats[1] * invn - mu * mu;
    float sc = rsqrtf(var + EPSF);
    for (int i = blockIdx.x * blockDim.x + threadIdx.x; i < n; i += gridDim.x * blockDim.x)
        y[i] = (x[i] - mu) * sc;
}

// w[co][ci][tap] -> wt[(ci*343+tap)*cop + co]  (fp32, pad co to cop)
__global__ void k_wtrans(const float* __restrict__ w, int cout, int cin, int cop,
                         float* __restrict__ wt) {
    int total = cin * 343 * cop;
    for (int i = blockIdx.x * blockDim.x + threadIdx.x; i < total; i += gridDim.x * blockDim.x) {
        int co = i % cop;
        int rest = i / cop;  // ci*343 + tap
        float v = 0.f;
        if (co < cout) {
            int tap = rest % 343;
            int ci = rest / 343;
            v = w[(co * cin + ci) * 343 + tap];
        }
        wt[i] = v;
    }
}

// fp16 MFMA weights: wt[((tap*ncig + cig)*32 + co)*16 + cil]; co>=cout / ci>=cin zero
__global__ void k_wtrans_h(const float* __restrict__ w, ushort* __restrict__ wt,
                           int cout, int cin, int ncig) {
    int total = 343 * ncig * 512;
    int i = blockIdx.x * blockDim.x + threadIdx.x;
    if (i >= total) return;
    int cil = i & 15, co = (i >> 4) & 31;
    int rest = i >> 9;              // tap*ncig + cig
    int cig = rest % ncig, tap = rest / ncig;
    int ci = cig * 16 + cil;
    float v = 0.f;
    if (co < cout && ci < cin) v = w[(co * cin + ci) * 343 + tap];
    wt[i] = f2h(v);
}

// ---------------------------------------------------------------- generic MFMA conv
// Out-tile 8x8xTZ, 4 waves. NACC=2: wave w = z-plane w, acc0/acc1 = y halves.
// NACC=1: wave w -> z=(w&1), yhalf=(w>>1), acc0 only. K-step = 16 conceptual ci
// (BN/bias/relu/tensor-squares fused in LDS staging; OOB zeroed; fp16 operands).
// Verified layouts (m74/m101 + round-9 HW pass): A row=l&31, k=(l>>5)*8+j;
// B col=l&31; C/D col=lane&31, row=(reg&3)+8*(reg>>2)+4*(lane>>5).
template <int COA, int NCIG, int ST, int TZ, int NACC>
__global__ __launch_bounds__(256) void k_mconv(
    const float* __restrict__ in, const ushort* __restrict__ wt, float* __restrict__ out,
    const float* __restrict__ scl, const float* __restrict__ bias,
    int Sin, int Sout, int Cst, int S, int V, int ntx) {
    constexpr int EXY = 7 * ST + 7;
    constexpr int EZ = (TZ - 1) * ST + 7;
    constexpr int NV = EZ * EXY * EXY;
    __shared__ __align__(16) ushort tile[NV * 16];

    int tid = threadIdx.x;
    int l = tid & 63, w = tid >> 6;
    int tb = blockIdx.x;
    int txb = tb % ntx, tyb = (tb / ntx) % ntx, tzb = tb / (ntx * ntx);
    int x0 = txb * 8, y0 = tyb * 8, z0 = tzb * TZ;
    int b = blockIdx.y;

    int co = l & 31, h = l >> 5, xl = l & 7, yl = (l >> 3) & 3;
    int zw = (NACC == 2) ? w : (w & 1);
    int yh = (NACC == 2) ? 0 : (w >> 1);

    int CIN = Cst + 9 * V;
    int sp_in = Sin * Sin * Sin;
    const float* yb = in + (long long)b * Cst * sp_in;
    int ox0 = x0 * ST - 3, oy0 = y0 * ST - 3, oz0 = z0 * ST - 3;

    f32x16 acc0 = {}, acc1 = {};

    for (int cig = 0; cig < NCIG; ++cig) {
        __syncthreads();  // protect prior-iteration LDS reads
        for (int idx = tid; idx < NV; idx += 256) {
            int vz = idx / (EXY * EXY);
            int r = idx - vz * EXY * EXY;
            int vy = r / EXY, vx = r - vy * EXY;
            int gz = oz0 + vz, gy = oy0 + vy, gx = ox0 + vx;
            bool inb = (unsigned)gx < (unsigned)Sin && (unsigned)gy < (unsigned)Sin &&
                       (unsigned)gz < (unsigned)Sin;
            int off = inb ? ((gz * Sin + gy) * Sin + gx) : 0;
            float fv[16];
#pragma unroll
            for (int cc = 0; cc < 16; ++cc) {
                int ci = cig * 16 + cc;
                float v = 0.f;
                if (inb && ci < CIN) {
                    if (ci < S) {
                        v = fmaxf(yb[(long long)ci * sp_in + off] * scl[ci] + bias[ci], 0.f);
                    } else if (ci < Cst) {
                        v = yb[(long long)ci * sp_in + off] * scl[ci];
                    } else {
                        int q = ci - Cst;
                        int f = q / 9;
                        int rr = q - 9 * f;
                        int i3 = rr / 3, j3 = rr - 3 * i3;
                        int ca = S + 3 * f + i3, cb = S + 3 * f + j3;
                        v = (yb[(long long)ca * sp_in + off] * scl[ca]) *
                            (yb[(long long)cb * sp_in + off] * scl[cb]);
                    }
                }
                fv[cc] = v;
            }
            unsigned p[8];
#pragma unroll
            for (int j = 0; j < 8; ++j) p[j] = pkh(fv[2 * j], fv[2 * j + 1]);
            ushort* dst = &tile[idx * 16];
            ((uint4*)dst)[0] = make_uint4(p[0], p[1], p[2], p[3]);
            ((uint4*)dst)[1] = make_uint4(p[4], p[5], p[6], p[7]);
        }
        __syncthreads();

        const ushort* wb = wt + ((cig * 32 + co) * 16 + h * 8);
#pragma unroll 1
        for (int kz = 0; kz < 7; ++kz) {
#pragma unroll 1
            for (int ky = 0; ky < 7; ++ky) {
                int vb = ((zw * ST + kz) * EXY + ((yl + 4 * yh) * ST + ky)) * EXY + xl * ST;
                const ushort* ap = &tile[vb * 16 + h * 8];
                const ushort* wp = wb + (kz * 7 + ky) * 7 * (NCIG * 512);
#pragma unroll
                for (int kx = 0; kx < 7; ++kx) {
                    f16x8 a0 = *(const f16x8*)(ap + kx * 16);
                    f16x8 bfr = *(const f16x8*)(wp + kx * (NCIG * 512));
                    acc0 = __builtin_amdgcn_mfma_f32_32x32x16_f16(a0, bfr, acc0, 0, 0, 0);
                    if (NACC == 2) {
                        f16x8 a1 = *(const f16x8*)(ap + kx * 16 + 4 * ST * EXY * 16);
                        acc1 = __builtin_amdgcn_mfma_f32_32x32x16_f16(a1, bfr, acc1, 0, 0, 0);
                    }
                }
            }
        }
    }

    if (co < COA) {
        int sp = Sout * Sout * Sout;
        float* outp = out + ((long long)b * COA + co) * sp;
        int zz = z0 + zw;
#pragma unroll
        for (int r = 0; r < 16; ++r) {
            int m = (r & 3) + 8 * (r >> 2) + 4 * h;
            int xx = x0 + (m & 7);
            int yy = y0 + (m >> 3) + 4 * yh;
            outp[(zz * Sout + yy) * Sout + xx] = acc0[r];
            if (NACC == 2) outp[(zz * Sout + yy + 4) * Sout + xx] = acc1[r];
        }
    }
}

// ---------------------------------------------------------------- fused direct conv (fp32)
template <int COUT, int COP, int ST>
__global__ __launch_bounds__(256) void k_conv(
    const float* __restrict__ in, const float* __restrict__ wt, float* __restrict__ out,
    const float* __restrict__ scl, const float* __restrict__ bias,
    int B, int CIN, int Cst, int S, int Vc, int Sin, int Sout,
    int ntx, int nty, int cpc, int mode, int atomic_flag) {
    constexpr int E = 7 * ST + 7;
    __shared__ float tile[E * E * E];

    int t = blockIdx.x;
    int txb = t % ntx;
    int tyb = (t / ntx) % nty;
    int tzb = t / (ntx * nty);
    int b = blockIdx.y;
    int c0 = blockIdx.z * cpc;
    int c1 = min(CIN, c0 + cpc);
    int tid = threadIdx.x;
    int tx = tid & 7, ty = (tid >> 3) & 7, tzq = tid >> 6;

    float acc0[COUT], acc1[COUT];
#pragma unroll
    for (int i = 0; i < COUT; i++) { acc0[i] = 0.f; acc1[i] = 0.f; }

    int x0 = txb * 8 * ST - 3, y0 = tyb * 8 * ST - 3, z0 = tzb * 8 * ST - 3;
    int sp_in = Sin * Sin * Sin;

    for (int ci = c0; ci < c1; ++ci) {
        int ca = ci, cb = 0, kind = 1;
        float sa = 1.f, sb = 0.f, bv = 0.f;
        if (mode != 0) {
            int C = S + 3 * Vc;
            if (ci < S) {
                kind = 0; sa = scl[ci]; bv = bias[ci];
            } else if (ci < C) {
                kind = 1; sa = scl[ci];
            } else {
                int q = ci - C;
                int f = q / 9;
                int r = q - 9 * f;
                int i3 = r / 3;
                int j3 = r - 3 * i3;
                ca = S + 3 * f + i3;
                cb = S + 3 * f + j3;
                sa = scl[ca];
                sb = scl[cb];
                kind = 2;
            }
        }
        const float* pa = in + ((long long)b * Cst + ca) * sp_in;
        const float* pb = in + ((long long)b * Cst + cb) * sp_in;

        __syncthreads();
        for (int idx = tid; idx < E * E * E; idx += 256) {
            int iz = idx / (E * E);
            int r = idx - iz * E * E;
            int iy = r / E;
            int ix = r - iy * E;
            int gx = x0 + ix, gy = y0 + iy, gz = z0 + iz;
            float v = 0.f;
            if ((unsigned)gx < (unsigned)Sin && (unsigned)gy < (unsigned)Sin &&
                (unsigned)gz < (unsigned)Sin) {
                int off = (gz * Sin + gy) * Sin + gx;
                float va = pa[off];
                if (kind == 0)
                    v = fmaxf(va * sa + bv, 0.f);
                else if (kind == 1)
                    v = va * sa;
                else
                    v = (va * sa) * (pb[off] * sb);
            }
            tile[idx] = v;
        }
        __syncthreads();

        const float* wci = wt + (long long)ci * 343 * COP;
#pragma unroll 1
        for (int kz = 0; kz < 7; ++kz) {
#pragma unroll 1
            for (int ky = 0; ky < 7; ++ky) {
                int r0 = ((tzq * ST + kz) * E + (ty * ST + ky)) * E + tx * ST;
                int r1 = r0 + 4 * ST * E * E;
                const float* wrow = wci + (kz * 7 + ky) * 7 * COP;
#pragma unroll
                for (int kx = 0; kx < 7; ++kx) {
                    float v0 = tile[r0 + kx];
                    float v1 = tile[r1 + kx];
                    const float* wp = wrow + kx * COP;
#pragma unroll
                    for (int co = 0; co < COUT; ++co) {
                        float w = wp[co];
                        acc0[co] = fmaf(w, v0, acc0[co]);
                        acc1[co] = fmaf(w, v1, acc1[co]);
                    }
                }
            }
        }
    }

    int ox = txb * 8 + tx, oy = tyb * 8 + ty;
    int oz0 = tzb * 8 + tzq, oz1 = oz0 + 4;
    if (ox >= Sout || oy >= Sout) return;
    int sp = Sout * Sout * Sout;
    long long obase = (long long)b * COUT * sp;
    int p0 = (oz0 * Sout + oy) * Sout + ox;
    int p1 = (oz1 * Sout + oy) * Sout + ox;
    if (atomic_flag) {
#pragma unroll
        for (int co = 0; co < COUT; co++) {
            if (oz0 < Sout) atomicAdd(&out[obase + (long long)co * sp + p0], acc0[co]);
            if (oz1 < Sout) atomicAdd(&out[obase + (long long)co * sp + p1], acc1[co]);
        }
    } else {
#pragma unroll
        for (int co = 0; co < COUT; co++) {
            if (oz0 < Sout) out[obase + (long long)co * sp + p0] = acc0[co];
            if (oz1 < Sout) out[obase + (long long)co * sp + p1] = acc1[co];
        }
    }
}

// ---------------------------------------------------------------- SE(3) BN stats
__global__ void k_sumsq(const float* __restrict__ y, int B, int C, int sp,
                        float* __restrict__ ssq) {
    int c = blockIdx.y;
    float s = 0.f;
    int n = B * sp;
    for (int e = blockIdx.x * blockDim.x + threadIdx.x; e < n; e += gridDim.x * blockDim.x) {
        int b = e / sp;
        int p = e - b * sp;
        float v = y[((long long)b * C + c) * sp + p];
        s += v * v;
    }
    s = waveReduceSum(s);
    __shared__ float sh[4];
    int lane = threadIdx.x & 63, w = threadIdx.x >> 6;
    if (lane == 0) sh[w] = s;
    __syncthreads();
    if (threadIdx.x == 0) {
        float a = 0.f;
        int nw = blockDim.x >> 6;
        for (int i = 0; i < nw; i++) a += sh[i];
        atomicAdd(&ssq[c], a);
    }
}

__global__ void k_scales(const float* __restrict__ ssq, const float* __restrict__ bnw,
                         int s, int v, float invN, float* __restrict__ scale) {
    int t = threadIdx.x;
    if (t < s) {
        float n = ssq[t] * invN;
        scale[t] = bnw[t] * rsqrtf(n + EPSF);
    }
    if (t < v) {
        float n = (ssq[s + 3 * t] + ssq[s + 3 * t + 1] + ssq[s + 3 * t + 2]) * invN * (1.f / 3.f);
        float sc = bnw[s + t] * rsqrtf(n + EPSF);
        scale[s + 3 * t] = sc;
        scale[s + 3 * t + 1] = sc;
        scale[s + 3 * t + 2] = sc;
    }
}

// layer 6 BN scale + spatial mean + batch norm + affine -> (32,10)
__global__ void k_final(const float* __restrict__ y, const float* __restrict__ scale,
                        const float* __restrict__ gamma, const float* __restrict__ beta,
                        float* __restrict__ out) {
    __shared__ float m[320];
    __shared__ float mu[10], isd[10];
    int t = threadIdx.x;
    if (t < 320) {
        int b = t / 10, c = t % 10;
        const float* yp = y + (b * 10 + c) * 64;
        float s = 0.f;
        for (int p = 0; p < 64; p++) s += yp[p];
        m[t] = s * (1.f / 64.f) * scale[c];
    }
    __syncthreads();
    if (t < 10) {
        float a = 0.f, a2 = 0.f;
        for (int b = 0; b < 32; b++) {
            float vv = m[b * 10 + t];
            a += vv;
            a2 += vv * vv;
        }
        a *= (1.f / 32.f);
        a2 = a2 * (1.f / 32.f) - a * a;
        mu[t] = a;
        isd[t] = rsqrtf(a2 + EPSF);
    }
    __syncthreads();
    if (t < 320) {
        int c = t % 10;
        out[t] = (m[t] - mu[c]) * isd[c] * gamma[c] + beta[c];
    }
}

// ---------------------------------------------------------------- driver
extern "C" void kernel_launch(void* const* d_in, const int* in_sizes, int n_in,
                              void* d_out, int out_size, void* d_ws, size_t ws_size,
                              hipStream_t stream) {
    if (ws_size < (size_t)WS_NEED) {
        k_zero_out<<<1, 256, 0, stream>>>((float*)d_out, out_size);
        return;
    }

    const float* x = (const float*)d_in[0];

    int iw[7], ibnw[7], ibias[6];
    if (in_sizes[2] == 6) {
        for (int i = 0; i < 7; i++) { iw[i] = 1 + 2 * i; ibnw[i] = 2 + 2 * i; }
    } else {
        for (int i = 0; i < 7; i++) { iw[i] = 1 + i; ibnw[i] = 8 + i; }
    }
    for (int i = 0; i < 6; i++) ibias[i] = 15 + i;
    const float* gamma = (const float*)d_in[21];
    const float* beta = (const float*)d_in[22];

    char* ws = (char*)d_ws;
    float* rodd = (float*)(ws + ODD_OFF);    // X_norm, Y1, Y3, Y5
    float* reven = (float*)(ws + EVEN_OFF);  // Y0, Y2, Y4, Y6
    float* wtall = (float*)(ws + WT_OFF);
    float* stats = (float*)(ws + STATS_OFF);
    // fp16 MFMA weights reuse layers 1-3's (now unused) fp32 weight slots
    ushort* wt_l1 = (ushort*)(wtall + 4116);     // needs 702,464 B  < 1.05 MB slot
    ushort* wt_l2 = (ushort*)(wtall + 273028);   // needs 1,756,160 B < 2.69 MB slot
    ushort* wt_l3 = (ushort*)(wtall + 945308);   // needs 1,756,160 B < 3.07 MB slot

    hipMemsetAsync(stats, 0, 1024 * sizeof(float), stream);

    const int nIn = 32 * 64 * 64 * 64;
    k_input_stats<<<2048, 256, 0, stream>>>(x, nIn, stats);
    k_normalize<<<2048, 256, 0, stream>>>(x, nIn, 1.0f / (float)nIn, stats, rodd);

    static const int cinA[7] = {1, 28, 70, 70, 84, 84, 98};
    static const int coutA[7] = {10, 25, 25, 30, 30, 35, 10};
    static const int copA[7] = {12, 28, 28, 32, 32, 36, 12};
    static const int sA[7] = {4, 10, 10, 12, 12, 14, 10};
    static const int vA[7] = {2, 5, 5, 6, 6, 7, 0};
    static const int SinA[7] = {64, 32, 32, 16, 16, 8, 8};
    static const int SoutA[7] = {32, 32, 16, 16, 8, 8, 4};
    static const int ntxA[7] = {4, 4, 2, 2, 1, 1, 1};
    static const int chA[7] = {1, 1, 1, 1, 28, 28, 49};   // MFMA layers: no chunking
    static const long long wtoffA[7] = {0, 4116, 273028, 945308, 1713628, 2635612, 3672844};
    static const int cstA[7] = {1, 10, 25, 25, 30, 30, 35};

    for (int i = 0; i < 7; i++) {
        if (i >= 1 && i <= 3) continue;  // layers 1-3 use fp16 weights
        int total = cinA[i] * 343 * copA[i];
        int g = (total + 255) / 256;
        if (g > 1024) g = 1024;
        k_wtrans<<<g, 256, 0, stream>>>((const float*)d_in[iw[i]], coutA[i], cinA[i], copA[i],
                                        wtall + wtoffA[i]);
    }
    k_wtrans_h<<<1372, 256, 0, stream>>>((const float*)d_in[iw[1]], wt_l1, 25, 28, 2);
    k_wtrans_h<<<3430, 256, 0, stream>>>((const float*)d_in[iw[2]], wt_l2, 25, 70, 5);
    k_wtrans_h<<<3430, 256, 0, stream>>>((const float*)d_in[iw[3]], wt_l3, 30, 70, 5);

    for (int i = 0; i < 7; i++) {
        int sp = SoutA[i] * SoutA[i] * SoutA[i];
        int cpc = (cinA[i] + chA[i] - 1) / chA[i];
        int atom = (chA[i] > 1) ? 1 : 0;
        float* Yin = (i == 0) ? rodd : ((i & 1) ? reven : rodd);
        float* Yout = (i & 1) ? rodd : reven;
        const float* scl_in = (i == 0) ? nullptr : (stats + 16 + (i - 1) * 128 + 64);
        const float* bias_in = (i == 0) ? nullptr : (const float*)d_in[ibias[i - 1]];
        int mode = (i == 0) ? 0 : 1;
        int S_in = (i == 0) ? 1 : sA[i - 1];
        int V_in = (i == 0) ? 0 : vA[i - 1];

        if (atom) hipMemsetAsync(Yout, 0, (size_t)32 * coutA[i] * sp * 4, stream);
        dim3 g(ntxA[i] * ntxA[i] * ntxA[i], 32, chA[i]);
        const float* wtb = wtall + wtoffA[i];
        switch (i) {
            case 0: k_conv<10, 12, 2><<<g, 256, 0, stream>>>(Yin, wtb, Yout, scl_in, bias_in, 32, cinA[i], cstA[i], S_in, V_in, SinA[i], SoutA[i], ntxA[i], ntxA[i], cpc, mode, atom); break;
            case 1:  // stride-1, 32^3, cin 28 (2 cig), cout 25
                k_mconv<25, 2, 1, 4, 2><<<dim3(128, 32), 256, 0, stream>>>(
                    Yin, wt_l1, Yout, scl_in, bias_in, 32, 32, 10, 4, 2, 4);
                break;
            case 2:  // stride-2, 32->16, cin 70 (5 cig), cout 25
                k_mconv<25, 5, 2, 2, 1><<<dim3(32, 32), 256, 0, stream>>>(
                    Yin, wt_l2, Yout, scl_in, bias_in, 32, 16, 25, 10, 5, 2);
                break;
            case 3:  // stride-1, 16^3, cin 70 (5 cig), cout 30
                k_mconv<30, 5, 1, 4, 2><<<dim3(16, 32), 256, 0, stream>>>(
                    Yin, wt_l3, Yout, scl_in, bias_in, 16, 16, 25, 10, 5, 2);
                break;
            case 4: k_conv<30, 32, 2><<<g, 256, 0, stream>>>(Yin, wtb, Yout, scl_in, bias_in, 32, cinA[i], cstA[i], S_in, V_in, SinA[i], SoutA[i], ntxA[i], ntxA[i], cpc, mode, atom); break;
            case 5: k_conv<35, 36, 1><<<g, 256, 0, stream>>>(Yin, wtb, Yout, scl_in, bias_in, 32, cinA[i], cstA[i], S_in, V_in, SinA[i], SoutA[i], ntxA[i], ntxA[i], cpc, mode, atom); break;
            case 6: k_conv<10, 12, 2><<<g, 256, 0, stream>>>(Yin, wtb, Yout, scl_in, bias_in, 32, cinA[i], cstA[i], S_in, V_in, SinA[i], SoutA[i], ntxA[i], ntxA[i], cpc, mode, atom); break;
        }

        float* ssq = stats + 16 + i * 128;
        float* scl = ssq + 64;
        int n = 32 * sp;
        int nblk = (n + 255) / 256;
        if (nblk > 256) nblk = 256;
        k_sumsq<<<dim3(nblk, coutA[i]), 256, 0, stream>>>(Yout, 32, coutA[i], sp, ssq);
        k_scales<<<1, 64, 0, stream>>>(ssq, (const float*)d_in[ibnw[i]], sA[i], vA[i],
                                       1.0f / (float)(32 * sp), scl);
    }

    float* scl6 = stats + 16 + 6 * 128 + 64;
    k_final<<<1, 512, 0, stream>>>(reven, scl6, gamma, beta, (float*)d_out);
}